// Round 11
// baseline (209.754 us; speedup 1.0000x reference)
//
#include <hip/hip_runtime.h>
#include <math.h>

// Problem constants (match reference).
#define BDIM 4096
#define TDIM 2048
#define NBLK 512          // k1 grid: BDIM / 8  (partial stays [512][2048] = 4 MB)

// gamma powers as exact compile-time folded constants
constexpr double gpow(int e) {
    double r = 1.0;
    for (int i = 0; i < e; ++i) r *= 0.99;
    return r;
}

__device__ __forceinline__ float logsig_fast(float x) {
    // log(sigmoid(x)) = min(x,0) - log(1 + exp(-|x|)); HW transcendentals.
    float z = __expf(-fabsf(x));
    return fminf(x, 0.0f) - __logf(1.0f + z);
}

__device__ __forceinline__ float clip5(float x) {
    return fminf(fmaxf(x, -5.0f), 5.0f);
}

// ---------------------------------------------------------------------------
// K1: WAVE-PER-ROW reverse discounted scan. Each wave owns one full row:
// lane holds 32 contiguous cols, 31-FMA local suffix scan, then a 6-step
// weighted shuffle scan (factor gamma^(32*2^s)) completes the row IN-WAVE.
// ZERO barriers in the hot path (vs barrier-per-row in all prior versions,
// which lockstepped 16 waves and made memory traffic bursty). Waves run
// free; the only block-level step is the LDS merge of 8 waves' diffs.
// Blocks 0/1 zero colsum/obj (replaces memsets).
// ---------------------------------------------------------------------------
__global__ __launch_bounds__(512, 4) void k1_scan(
    const float* __restrict__ logits,
    const float* __restrict__ weight,
    const float* __restrict__ baselines,
    float* __restrict__ cum_out,
    float* __restrict__ partial,
    float* __restrict__ colsum,
    float* __restrict__ obj)
{
    const int tid  = threadIdx.x;     // 0..511
    const int lane = tid & 63;
    const int wave = tid >> 6;        // 0..7 (= row within block)

    // in-kernel zeroing (k2/k3/k4 are stream-ordered after k1)
    if (blockIdx.x == 0) {
        *reinterpret_cast<float4*>(colsum + tid * 4) = make_float4(0.f, 0.f, 0.f, 0.f);
    }
    if (blockIdx.x == 1) {
        *reinterpret_cast<float4*>(obj + tid * 4) = make_float4(0.f, 0.f, 0.f, 0.f);
    }

    const float G = 0.99f;
    // shuffle-scan factors gamma^(32*2^s), s=0..5
    const float fsw[6] = {(float)gpow(32),  (float)gpow(64),  (float)gpow(128),
                          (float)gpow(256), (float)gpow(512), (float)gpow(1024)};
    // gt[k] = gamma^(32-k), k=0..31
    const float gt[32] = {
        (float)gpow(32), (float)gpow(31), (float)gpow(30), (float)gpow(29),
        (float)gpow(28), (float)gpow(27), (float)gpow(26), (float)gpow(25),
        (float)gpow(24), (float)gpow(23), (float)gpow(22), (float)gpow(21),
        (float)gpow(20), (float)gpow(19), (float)gpow(18), (float)gpow(17),
        (float)gpow(16), (float)gpow(15), (float)gpow(14), (float)gpow(13),
        (float)gpow(12), (float)gpow(11), (float)gpow(10), (float)gpow(9),
        (float)gpow(8),  (float)gpow(7),  (float)gpow(6),  (float)gpow(5),
        (float)gpow(4),  (float)gpow(3),  (float)gpow(2),  (float)gpow(1)};

    // column-major diff accumulator: cacc[m*64 + l] = col l*32+m
    // (bank = lane&31 -> 2 lanes/bank on every atomic step = conflict-free)
    __shared__ __align__(16) float cacc[TDIM];   // 8 KB

    // zero LDS merge buffer
    *reinterpret_cast<float4*>(&cacc[tid * 4]) = make_float4(0.f, 0.f, 0.f, 0.f);
    __syncthreads();

    const int row = blockIdx.x * 8 + wave;
    const size_t rbase = (size_t)row * TDIM + (size_t)lane * 32;

    // load this lane's 32-col chunk of all three streams (24 float4 loads,
    // all independent — deep MLP, no barrier between issue and use)
    float4 xq[8], wq[8], bq[8];
#pragma unroll
    for (int j = 0; j < 8; ++j) xq[j] = *reinterpret_cast<const float4*>(logits + rbase + j * 4);
#pragma unroll
    for (int j = 0; j < 8; ++j) wq[j] = *reinterpret_cast<const float4*>(weight + rbase + j * 4);
#pragma unroll
    for (int j = 0; j < 8; ++j) bq[j] = *reinterpret_cast<const float4*>(baselines + rbase + j * 4);

    // wr[k] = w*logsig(x), then in-place local suffix scan
    float wr[32];
#pragma unroll
    for (int j = 0; j < 8; ++j) {
        wr[j * 4 + 0] = wq[j].x * logsig_fast(xq[j].x);
        wr[j * 4 + 1] = wq[j].y * logsig_fast(xq[j].y);
        wr[j * 4 + 2] = wq[j].z * logsig_fast(xq[j].z);
        wr[j * 4 + 3] = wq[j].w * logsig_fast(xq[j].w);
    }
#pragma unroll
    for (int k = 30; k >= 0; --k) wr[k] = fmaf(G, wr[k + 1], wr[k]);
    // wr[k] now = loc[k] = sum_{s>=k} g^(s-k) r[lane*32+s]

    // wave-level weighted suffix scan over per-lane totals
    float v = wr[0];
#pragma unroll
    for (int s = 0; s < 6; ++s) {
        const int o = 1 << s;
        float up = __shfl_down(v, (unsigned)o, 64);
        if (lane + o < 64) v = fmaf(fsw[s], up, v);
    }
    // v = full suffix cum at this lane's first col; tail = cum at col+32
    const float vn = __shfl_down(v, 1, 64);
    const float tail = (lane == 63) ? 0.0f : vn;

    float c[32];
#pragma unroll
    for (int k = 0; k < 32; ++k) c[k] = fmaf(gt[k], tail, wr[k]);

    // store cum (8 x float4, wave covers the full 8 KB row chunk)
#pragma unroll
    for (int j = 0; j < 8; ++j) {
        *reinterpret_cast<float4*>(cum_out + rbase + j * 4) =
            make_float4(c[j * 4 + 0], c[j * 4 + 1], c[j * 4 + 2], c[j * 4 + 3]);
    }

    // unpack baselines to a statically-indexed array (rule: no dynamic reg idx)
    float bv[32];
#pragma unroll
    for (int j = 0; j < 8; ++j) {
        bv[j * 4 + 0] = bq[j].x; bv[j * 4 + 1] = bq[j].y;
        bv[j * 4 + 2] = bq[j].z; bv[j * 4 + 3] = bq[j].w;
    }

    // merge diff into LDS (column-major: bank = lane&31, conflict-free)
#pragma unroll
    for (int k = 0; k < 32; ++k) {
        atomicAdd(&cacc[k * 64 + lane], c[k] - bv[k]);
    }
    __syncthreads();

    // write per-block partial row: partial[blockIdx][col], col = tid*4 + e
    {
        const int col0 = tid * 4;
        float4 p;
        // col = l*32 + m  ->  cacc[m*64 + l]
        p.x = cacc[((col0 + 0) & 31) * 64 + ((col0 + 0) >> 5)];
        p.y = cacc[((col0 + 1) & 31) * 64 + ((col0 + 1) >> 5)];
        p.z = cacc[((col0 + 2) & 31) * 64 + ((col0 + 2) >> 5)];
        p.w = cacc[((col0 + 3) & 31) * 64 + ((col0 + 3) >> 5)];
        *reinterpret_cast<float4*>(partial + (size_t)blockIdx.x * TDIM + col0) = p;
    }
}

// ---------------------------------------------------------------------------
// K2: colsum[col] = sum over 512 partial rows (32 slices x 16 rows).
// ---------------------------------------------------------------------------
__global__ __launch_bounds__(256) void k2_colsum(
    const float* __restrict__ partial, float* __restrict__ colsum)
{
    const int gid = blockIdx.x * 256 + threadIdx.x;   // 0..65535
    const int col = gid & (TDIM - 1);
    const int slc = gid >> 11;                        // 0..31
    const float* p = partial + (size_t)slc * 16 * TDIM + col;
    float s = 0.0f;
#pragma unroll
    for (int i = 0; i < 16; ++i) s += p[(size_t)i * TDIM];
    atomicAdd(colsum + col, s);
}

// ---------------------------------------------------------------------------
// K3: per-y-block objective partials — NO atomics.
// grid (4, 512) = 2048 blocks = 32 waves/CU; 8 rows/thread, float2 cols.
// ---------------------------------------------------------------------------
#define K3_ROWS 8
__global__ __launch_bounds__(256) void k3_part(
    const float* __restrict__ cum,
    const float* __restrict__ baselines,
    const float* __restrict__ lp,
    const float* __restrict__ colsum,
    float* __restrict__ objpart)
{
    const int c2 = (blockIdx.x * 256 + threadIdx.x) * 2;   // column pair
    const int yb = blockIdx.y;                             // 0..511
    const int r0 = yb * K3_ROWS;
    const float inv = 1.0f / (float)BDIM;
    float2 ms = *reinterpret_cast<const float2*>(colsum + c2);
    const float m0 = ms.x * inv, m1 = ms.y * inv;

    float a0 = 0.0f, a1 = 0.0f;
    size_t idx = (size_t)r0 * TDIM + c2;
#pragma unroll
    for (int r = 0; r < K3_ROWS; ++r, idx += TDIM) {
        float2 c = *reinterpret_cast<const float2*>(cum + idx);
        float2 b = *reinterpret_cast<const float2*>(baselines + idx);
        float2 l = *reinterpret_cast<const float2*>(lp + idx);
        a0 = fmaf(clip5(c.x - b.x - m0), l.x, a0);
        a1 = fmaf(clip5(c.y - b.y - m1), l.y, a1);
    }
    *reinterpret_cast<float2*>(objpart + (size_t)yb * TDIM + c2) = make_float2(a0, a1);
}

// ---------------------------------------------------------------------------
// K4: obj[col] = sum over 512 objpart rows (32 slices x 16 rows) — k2 clone.
// ---------------------------------------------------------------------------
__global__ __launch_bounds__(256) void k4_objsum(
    const float* __restrict__ objpart, float* __restrict__ obj)
{
    const int gid = blockIdx.x * 256 + threadIdx.x;   // 0..65535
    const int col = gid & (TDIM - 1);
    const int slc = gid >> 11;                        // 0..31
    const float* p = objpart + (size_t)slc * 16 * TDIM + col;
    float s = 0.0f;
#pragma unroll
    for (int i = 0; i < 16; ++i) s += p[(size_t)i * TDIM];
    atomicAdd(obj + col, s);
}

extern "C" void kernel_launch(void* const* d_in, const int* in_sizes, int n_in,
                              void* d_out, int out_size, void* d_ws, size_t ws_size,
                              hipStream_t stream) {
    const float* log_probs = (const float*)d_in[0];   // [B,T]
    const float* logits    = (const float*)d_in[1];   // [B,T,1]
    const float* weight    = (const float*)d_in[2];   // [B,T]
    const float* baselines = (const float*)d_in[3];   // [B,T,1]

    float* out = (float*)d_out;
    float* obj = out;            // [T]
    float* cum = out + TDIM;     // [B,T]

    float* partial = (float*)d_ws;                       // [512][2048] = 4 MB
    float* colsum  = partial + (size_t)NBLK * TDIM;      // 2048 floats

    // k1 writes partial (colacc) and zeroes colsum/obj.
    k1_scan<<<NBLK, 512, 0, stream>>>(logits, weight, baselines, cum, partial, colsum, obj);
    // k2 consumes partial -> colsum.
    k2_colsum<<<256, 256, 0, stream>>>(partial, colsum);
    // k3 reuses partial as objpart (k2 finished reading it; stream-ordered).
    k3_part<<<dim3(4, 512), 256, 0, stream>>>(cum, baselines, log_probs, colsum, partial);
    // k4 reduces objpart -> obj.
    k4_objsum<<<256, 256, 0, stream>>>(partial, obj);
}

// Round 13
// 168.938 us; speedup vs baseline: 1.2416x; 1.2416x over previous
//
#include <hip/hip_runtime.h>
#include <math.h>

// Problem constants (match reference).
#define BDIM 4096
#define TDIM 2048
#define NBLK 512          // k1 grid: BDIM / 8  (partial stays [512][2048] = 4 MB)

// gamma powers as exact compile-time folded constants
constexpr double gpow(int e) {
    double r = 1.0;
    for (int i = 0; i < e; ++i) r *= 0.99;
    return r;
}

__device__ __forceinline__ float logsig_fast(float x) {
    // log(sigmoid(x)) = min(x,0) - log(1 + exp(-|x|)); HW transcendentals.
    float z = __expf(-fabsf(x));
    return fminf(x, 0.0f) - __logf(1.0f + z);
}

__device__ __forceinline__ float clip5(float x) {
    return fminf(fmaxf(x, -5.0f), 5.0f);
}

// ---------------------------------------------------------------------------
// K1: reverse discounted scan, SINGLE-BARRIER structure.
// Round-8 math (1024 thr, 2 cols/thread, 16 waves, verified) restructured:
//   phase 1: ALL 24 loads issued upfront (no barrier between issue & use —
//            in the old per-row loop, the compiler's vmcnt(0) drain at each
//            __syncthreads made every prefetch synchronous: the 42us pin).
//   phase 2: 8 independent wave-scans (8-way ILP on shuffles), ONE barrier.
//   phase 3: per-wave carry chains (wave-uniform loop), stores all deferred.
// Blocks 0/1 zero colsum/obj (replaces memsets).
// ---------------------------------------------------------------------------
__global__ __launch_bounds__(1024, 4) void k1_scan(
    const float* __restrict__ logits,
    const float* __restrict__ weight,
    const float* __restrict__ baselines,
    float* __restrict__ cum_out,
    float* __restrict__ partial,
    float* __restrict__ colsum,
    float* __restrict__ obj)
{
    const int tid  = threadIdx.x;     // 0..1023
    const int lane = tid & 63;
    const int wave = tid >> 6;        // 0..15
    const int t0   = tid * 2;         // 2 contiguous columns per thread

    // in-kernel zeroing (k2/k3/k4 are stream-ordered after k1)
    if (blockIdx.x == 0) {
        *reinterpret_cast<float2*>(colsum + t0) = make_float2(0.f, 0.f);
    }
    if (blockIdx.x == 1) {
        *reinterpret_cast<float2*>(obj + t0) = make_float2(0.f, 0.f);
    }

    const float G    = 0.99f;
    const float G128 = (float)gpow(128);       // one wave spans 64*2 = 128 cols
    const float LOG2G = -0.014499569695115089f;  // log2(0.99)
    const float gk[2] = {(float)gpow(2), (float)gpow(1)};
    // shuffle-scan factors gamma^(2*2^s), s=0..5
    const float fs[6] = {(float)gpow(2),  (float)gpow(4),  (float)gpow(8),
                         (float)gpow(16), (float)gpow(32), (float)gpow(64)};
    // gamma^((64-lane)*2)
    const float lane_pow = exp2f((float)((64 - lane) * 2) * LOG2G);

    __shared__ float wsum[8][16];   // [row][wave]

    const int row0 = blockIdx.x * 8;
    const size_t base0 = (size_t)row0 * TDIM + t0;

    // ---- phase 1: issue ALL loads upfront (24 independent float2 loads) ----
    float2 xv[8], wv[8], bv[8];
#pragma unroll
    for (int r = 0; r < 8; ++r) {
        const size_t base = base0 + (size_t)r * TDIM;
        xv[r] = *reinterpret_cast<const float2*>(logits + base);
        wv[r] = *reinterpret_cast<const float2*>(weight + base);
        bv[r] = *reinterpret_cast<const float2*>(baselines + base);
    }

    // wr = w * logsig(x); local 2-elem suffix scan
    float loc0[8], loc1[8], v[8];
#pragma unroll
    for (int r = 0; r < 8; ++r) {
        float w0 = wv[r].x * logsig_fast(xv[r].x);
        float w1 = wv[r].y * logsig_fast(xv[r].y);
        loc1[r] = w1;
        loc0[r] = fmaf(G, w1, w0);
        v[r]    = loc0[r];
    }

    // ---- phase 2: 8 independent wave-level weighted suffix scans (ILP) ----
#pragma unroll
    for (int s = 0; s < 6; ++s) {
        const int o = 1 << s;
#pragma unroll
        for (int r = 0; r < 8; ++r) {
            float up = __shfl_down(v[r], (unsigned)o, 64);
            if (lane + o < 64) v[r] = fmaf(fs[s], up, v[r]);
        }
    }

    if (lane == 0) {
#pragma unroll
        for (int r = 0; r < 8; ++r) wsum[r][wave] = v[r];
    }
    __syncthreads();   // THE single barrier (vmem long drained -> cheap sync)

    // ---- phase 3: per-wave carry (wave-uniform loop, 8-way ILP) ----------
    // carry[r] = sum_{w2 > wave} gamma^(128*(w2-wave-1)) * wsum[r][w2]
    float carry[8];
#pragma unroll
    for (int r = 0; r < 8; ++r) carry[r] = 0.0f;
    for (int w2 = 15; w2 > wave; --w2) {
#pragma unroll
        for (int r = 0; r < 8; ++r) carry[r] = fmaf(G128, carry[r], wsum[r][w2]);
    }

    float colacc0 = 0.0f, colacc1 = 0.0f;
    float c0[8], c1[8];
#pragma unroll
    for (int r = 0; r < 8; ++r) {
        const float vfull = fmaf(lane_pow, carry[r], v[r]);
        const float vn = __shfl_down(vfull, 1, 64);
        const float tail = (lane == 63) ? carry[r] : vn;
        c0[r] = fmaf(gk[0], tail, loc0[r]);
        c1[r] = fmaf(gk[1], tail, loc1[r]);
        colacc0 += c0[r] - bv[r].x;
        colacc1 += c1[r] - bv[r].y;
    }

    // deferred stores: 8 x float2 cum + 1 x float2 partial
#pragma unroll
    for (int r = 0; r < 8; ++r) {
        *reinterpret_cast<float2*>(cum_out + base0 + (size_t)r * TDIM) =
            make_float2(c0[r], c1[r]);
    }
    *reinterpret_cast<float2*>(partial + (size_t)blockIdx.x * TDIM + t0) =
        make_float2(colacc0, colacc1);
}

// ---------------------------------------------------------------------------
// K2: colsum[col] = sum over 512 partial rows (32 slices x 16 rows).
// ---------------------------------------------------------------------------
__global__ __launch_bounds__(256) void k2_colsum(
    const float* __restrict__ partial, float* __restrict__ colsum)
{
    const int gid = blockIdx.x * 256 + threadIdx.x;   // 0..65535
    const int col = gid & (TDIM - 1);
    const int slc = gid >> 11;                        // 0..31
    const float* p = partial + (size_t)slc * 16 * TDIM + col;
    float s = 0.0f;
#pragma unroll
    for (int i = 0; i < 16; ++i) s += p[(size_t)i * TDIM];
    atomicAdd(colsum + col, s);
}

// ---------------------------------------------------------------------------
// K3: per-y-block objective partials — NO atomics.
// grid (4, 512) = 2048 blocks = 32 waves/CU; 8 rows/thread, float2 cols.
// ---------------------------------------------------------------------------
#define K3_ROWS 8
__global__ __launch_bounds__(256) void k3_part(
    const float* __restrict__ cum,
    const float* __restrict__ baselines,
    const float* __restrict__ lp,
    const float* __restrict__ colsum,
    float* __restrict__ objpart)
{
    const int c2 = (blockIdx.x * 256 + threadIdx.x) * 2;   // column pair
    const int yb = blockIdx.y;                             // 0..511
    const int r0 = yb * K3_ROWS;
    const float inv = 1.0f / (float)BDIM;
    float2 ms = *reinterpret_cast<const float2*>(colsum + c2);
    const float m0 = ms.x * inv, m1 = ms.y * inv;

    float a0 = 0.0f, a1 = 0.0f;
    size_t idx = (size_t)r0 * TDIM + c2;
#pragma unroll
    for (int r = 0; r < K3_ROWS; ++r, idx += TDIM) {
        float2 c = *reinterpret_cast<const float2*>(cum + idx);
        float2 b = *reinterpret_cast<const float2*>(baselines + idx);
        float2 l = *reinterpret_cast<const float2*>(lp + idx);
        a0 = fmaf(clip5(c.x - b.x - m0), l.x, a0);
        a1 = fmaf(clip5(c.y - b.y - m1), l.y, a1);
    }
    *reinterpret_cast<float2*>(objpart + (size_t)yb * TDIM + c2) = make_float2(a0, a1);
}

// ---------------------------------------------------------------------------
// K4: obj[col] = sum over 512 objpart rows (32 slices x 16 rows) — k2 clone.
// ---------------------------------------------------------------------------
__global__ __launch_bounds__(256) void k4_objsum(
    const float* __restrict__ objpart, float* __restrict__ obj)
{
    const int gid = blockIdx.x * 256 + threadIdx.x;   // 0..65535
    const int col = gid & (TDIM - 1);
    const int slc = gid >> 11;                        // 0..31
    const float* p = objpart + (size_t)slc * 16 * TDIM + col;
    float s = 0.0f;
#pragma unroll
    for (int i = 0; i < 16; ++i) s += p[(size_t)i * TDIM];
    atomicAdd(obj + col, s);
}

extern "C" void kernel_launch(void* const* d_in, const int* in_sizes, int n_in,
                              void* d_out, int out_size, void* d_ws, size_t ws_size,
                              hipStream_t stream) {
    const float* log_probs = (const float*)d_in[0];   // [B,T]
    const float* logits    = (const float*)d_in[1];   // [B,T,1]
    const float* weight    = (const float*)d_in[2];   // [B,T]
    const float* baselines = (const float*)d_in[3];   // [B,T,1]

    float* out = (float*)d_out;
    float* obj = out;            // [T]
    float* cum = out + TDIM;     // [B,T]

    float* partial = (float*)d_ws;                       // [512][2048] = 4 MB
    float* colsum  = partial + (size_t)NBLK * TDIM;      // 2048 floats

    // k1 writes partial (colacc) and zeroes colsum/obj.
    k1_scan<<<NBLK, 1024, 0, stream>>>(logits, weight, baselines, cum, partial, colsum, obj);
    // k2 consumes partial -> colsum.
    k2_colsum<<<256, 256, 0, stream>>>(partial, colsum);
    // k3 reuses partial as objpart (k2 finished reading it; stream-ordered).
    k3_part<<<dim3(4, 512), 256, 0, stream>>>(cum, baselines, log_probs, colsum, partial);
    // k4 reduces objpart -> obj.
    k4_objsum<<<256, 256, 0, stream>>>(partial, obj);
}